// Round 2
// baseline (1671.825 us; speedup 1.0000x reference)
//
#include <hip/hip_runtime.h>
#include <hip/hip_bf16.h>

typedef __hip_bfloat16 bf16;

#define D_MODEL 256
#define N_HEADS 8
#define DH      2048     // N_HEADS * D_MODEL
#define SEQ     2048
#define NTOK    16384    // B * SEQ
#define TOK     8        // tokens per block (kernel A)
#define DC      32       // head-dim chunk (kernel A)
#define XPAD    2        // X-tile row pad

// ---------------------------------------------------------------------------
// Kernel A: fused QKV projection + per-token 8x8 head-attention. fp32 in,
// fp32 math, writes x_att (scrambled transpose+reshape layout) as bf16 to ws.
// One block = 8 tokens, 256 threads.
// ---------------------------------------------------------------------------
__global__ __launch_bounds__(256) void qkv_attn_kernel(
    const float* __restrict__ Qin, const float* __restrict__ Kin,
    const float* __restrict__ Vin, const int* __restrict__ mask,
    const float* __restrict__ Wq, const float* __restrict__ bq,
    const float* __restrict__ Wk, const float* __restrict__ bk,
    const float* __restrict__ Wv, const float* __restrict__ bv,
    bf16* __restrict__ A)
{
    __shared__ float XqT[D_MODEL][TOK + XPAD];   // [c][t] transposed input tiles
    __shared__ float XkT[D_MODEL][TOK + XPAD];
    __shared__ float XvT[D_MODEL][TOK + XPAD];
    __shared__ float pq[TOK][N_HEADS][DC];       // partial q chunk
    __shared__ float pk[TOK][N_HEADS][DC];       // partial k chunk (pv reuses pq)
    __shared__ float sc[TOK][N_HEADS][N_HEADS];  // scores -> softmax weights

    const int tid  = threadIdx.x;
    const int tok0 = blockIdx.x * TOK;

    // Load X tiles transposed: thread = column c, loop tokens.
    {
        const int c = tid;
        #pragma unroll
        for (int t = 0; t < TOK; ++t) {
            XqT[c][t] = Qin[(size_t)(tok0 + t) * D_MODEL + c];
            XkT[c][t] = Kin[(size_t)(tok0 + t) * D_MODEL + c];
            XvT[c][t] = Vin[(size_t)(tok0 + t) * D_MODEL + c];
        }
    }
    for (int i = tid; i < TOK * N_HEADS * N_HEADS; i += 256)
        ((float*)sc)[i] = 0.0f;
    __syncthreads();

    const int dd = tid & (DC - 1);   // 0..31 within chunk
    const int h  = tid >> 5;         // 0..7 head

    // ---- Pass 1: accumulate scores sc[t][h][g] = q[t,h,:].k[t,g,:] ----
    for (int dc = 0; dc < D_MODEL; dc += DC) {
        const int n = h * D_MODEL + dc + dd;     // column in Wq/Wk
        float accq[TOK], acck[TOK];
        #pragma unroll
        for (int t = 0; t < TOK; ++t) { accq[t] = 0.f; acck[t] = 0.f; }
        #pragma unroll 4
        for (int c = 0; c < D_MODEL; ++c) {
            const float wq = Wq[(size_t)c * DH + n];
            const float wk = Wk[(size_t)c * DH + n];
            #pragma unroll
            for (int t = 0; t < TOK; ++t) {
                accq[t] = fmaf(XqT[c][t], wq, accq[t]);
                acck[t] = fmaf(XkT[c][t], wk, acck[t]);
            }
        }
        const float bq_n = bq[n];
        const float bk_n = bk[n];
        #pragma unroll
        for (int t = 0; t < TOK; ++t) {
            pq[t][h][dd] = accq[t] + bq_n;
            pk[t][h][dd] = acck[t] + bk_n;
        }
        __syncthreads();
        // score accumulation: 512 (t,h,g) tasks over 256 threads
        for (int task = tid; task < TOK * N_HEADS * N_HEADS; task += 256) {
            const int t  = task >> 6;
            const int hh = (task >> 3) & 7;
            const int g  = task & 7;
            float s = 0.f;
            #pragma unroll
            for (int d2 = 0; d2 < DC; ++d2)
                s = fmaf(pq[t][hh][d2], pk[t][g][d2], s);
            sc[t][hh][g] += s;
        }
        __syncthreads();
    }

    // ---- Softmax over g with per-token mask (masked -> uniform 1/8) ----
    if (tid < TOK * N_HEADS) {
        const int t  = tid >> 3;
        const int hh = tid & 7;
        if (mask[tok0 + t] == 0) {
            #pragma unroll
            for (int g = 0; g < N_HEADS; ++g) sc[t][hh][g] = 0.125f;
        } else {
            float mx = sc[t][hh][0];
            #pragma unroll
            for (int g = 1; g < N_HEADS; ++g) mx = fmaxf(mx, sc[t][hh][g]);
            float e[N_HEADS];
            float sum = 0.f;
            #pragma unroll
            for (int g = 0; g < N_HEADS; ++g) {
                e[g] = __expf((sc[t][hh][g] - mx) * (1.0f / 16.0f)); // /sqrt(256)
                sum += e[g];
            }
            const float inv = 1.0f / sum;
            #pragma unroll
            for (int g = 0; g < N_HEADS; ++g) sc[t][hh][g] = e[g] * inv;
        }
    }
    __syncthreads();

    // ---- Pass 2: v chunk + weighted sum + scrambled store ----
    for (int dc = 0; dc < D_MODEL; dc += DC) {
        const int n = h * D_MODEL + dc + dd;     // here h plays role of g
        float accv[TOK];
        #pragma unroll
        for (int t = 0; t < TOK; ++t) accv[t] = 0.f;
        #pragma unroll 4
        for (int c = 0; c < D_MODEL; ++c) {
            const float wv = Wv[(size_t)c * DH + n];
            #pragma unroll
            for (int t = 0; t < TOK; ++t)
                accv[t] = fmaf(XvT[c][t], wv, accv[t]);
        }
        const float bv_n = bv[n];
        #pragma unroll
        for (int t = 0; t < TOK; ++t)
            pq[t][h][dd] = accv[t] + bv_n;       // pv stored in pq
        __syncthreads();
        #pragma unroll
        for (int t = 0; t < TOK; ++t) {
            float o = 0.f;
            #pragma unroll
            for (int g = 0; g < N_HEADS; ++g)
                o = fmaf(sc[t][h][g], pq[t][g][dd], o);
            const int gtok = tok0 + t;
            const int b = gtok >> 11;            // / SEQ
            const int s = gtok & (SEQ - 1);
            // reference transpose+reshape: row = h*256 + s/8, col = (s%8)*256 + d
            const size_t row = (size_t)b * 2048 + (size_t)h * 256 + (s >> 3);
            const size_t col = (size_t)(s & 7) * 256 + dc + dd;
            A[row * DH + col] = __float2bfloat16(o);
        }
        __syncthreads();
    }
}

// ---------------------------------------------------------------------------
// Kernel B: out = A(16384x2048, bf16) @ Wo(2048x256, fp32) + bo, fp32 out.
// Block = 256 threads (one per output column), 16 rows per block.
// ---------------------------------------------------------------------------
#define RT   16
#define KC   64
#define APAD 4

__global__ __launch_bounds__(256) void outproj_kernel(
    const bf16* __restrict__ A, const float* __restrict__ Wo,
    const float* __restrict__ bo, float* __restrict__ Out)
{
    __shared__ float AT[KC][RT + APAD];          // [k][t] transposed A chunk
    const int tid = threadIdx.x;
    const size_t row0 = (size_t)blockIdx.x * RT;

    float acc[RT];
    #pragma unroll
    for (int t = 0; t < RT; ++t) acc[t] = 0.f;

    for (int kc = 0; kc < DH; kc += KC) {
        #pragma unroll
        for (int e = tid; e < RT * KC; e += 256) {   // 4 iters
            const int t = e >> 6;                    // e / KC
            const int k = e & (KC - 1);
            AT[k][t] = __bfloat162float(A[(row0 + t) * (size_t)DH + kc + k]);
        }
        __syncthreads();
        #pragma unroll 4
        for (int k = 0; k < KC; ++k) {
            const float w = Wo[(size_t)(kc + k) * D_MODEL + tid];
            #pragma unroll
            for (int t = 0; t < RT; ++t)
                acc[t] = fmaf(AT[k][t], w, acc[t]);
        }
        __syncthreads();
    }
    const float bias = bo[tid];
    #pragma unroll
    for (int t = 0; t < RT; ++t)
        Out[(row0 + t) * D_MODEL + tid] = acc[t] + bias;
}

// ---------------------------------------------------------------------------
extern "C" void kernel_launch(void* const* d_in, const int* in_sizes, int n_in,
                              void* d_out, int out_size, void* d_ws, size_t ws_size,
                              hipStream_t stream) {
    const float* query = (const float*)d_in[0];
    const float* key   = (const float*)d_in[1];
    const float* value = (const float*)d_in[2];
    const int*   mask  = (const int*)  d_in[3];
    const float* Wq = (const float*)d_in[4];  const float* bq = (const float*)d_in[5];
    const float* Wk = (const float*)d_in[6];  const float* bk = (const float*)d_in[7];
    const float* Wv = (const float*)d_in[8];  const float* bv = (const float*)d_in[9];
    const float* Wo = (const float*)d_in[10]; const float* bo = (const float*)d_in[11];
    float* out = (float*)d_out;
    bf16*  A   = (bf16*)d_ws;   // 16384*2048 bf16 = 64 MiB scrambled x_att

    qkv_attn_kernel<<<NTOK / TOK, 256, 0, stream>>>(
        query, key, value, mask, Wq, bq, Wk, bk, Wv, bv, A);
    outproj_kernel<<<NTOK / RT, 256, 0, stream>>>(A, Wo, bo, out);
}

// Round 3
// 427.548 us; speedup vs baseline: 3.9103x; 3.9103x over previous
//
#include <hip/hip_runtime.h>
#include <hip/hip_bf16.h>

typedef __hip_bfloat16 bf16;
typedef short bf16x8 __attribute__((ext_vector_type(8)));
typedef float f32x4 __attribute__((ext_vector_type(4)));

#define NCH 16   // 16 chunks x 128 permuted cols = 2048

#define MFMA16(a, b, c) __builtin_amdgcn_mfma_f32_16x16x32_bf16(a, b, c, 0, 0, 0)

__device__ __forceinline__ unsigned short f2us(float x) {
    union { __hip_bfloat16 h; unsigned short u; } cv;
    cv.h = __float2bfloat16(x);
    return cv.u;
}
__device__ __forceinline__ float us2f(unsigned short u) {
    union { unsigned short u; __hip_bfloat16 h; } cv;
    cv.u = u;
    return __bfloat162float(cv.h);
}

// ---------------------------------------------------------------------------
// prep: Wq/Wk/Wv fp32 -> bf16, transposed+permuted  WxT[p][c], p = d*8+h
//       (n = h*256+d).  biases permuted.  WoT (pure transpose) optional.
// ---------------------------------------------------------------------------
__global__ __launch_bounds__(256) void prep_kernel(
    const float* __restrict__ Wq, const float* __restrict__ Wk,
    const float* __restrict__ Wv, const float* __restrict__ bq,
    const float* __restrict__ bk, const float* __restrict__ bv,
    const float* __restrict__ Wo,
    bf16* __restrict__ WqT, bf16* __restrict__ WkT, bf16* __restrict__ WvT,
    float* __restrict__ bqp, float* __restrict__ bkp, float* __restrict__ bvp,
    bf16* __restrict__ WoT)
{
    const int bx = blockIdx.x, c = threadIdx.x;
    if (bx < 2048) {
        const int p = bx;
        const int n = (p & 7) * 256 + (p >> 3);
        WqT[p * 256 + c] = __float2bfloat16(Wq[(size_t)c * 2048 + n]);
        WkT[p * 256 + c] = __float2bfloat16(Wk[(size_t)c * 2048 + n]);
        WvT[p * 256 + c] = __float2bfloat16(Wv[(size_t)c * 2048 + n]);
        if (c == 0) { bqp[p] = bq[n]; bkp[p] = bk[n]; bvp[p] = bv[n]; }
    } else {
        const int cc = bx - 2048;   // output column 0..255
        #pragma unroll
        for (int i = 0; i < 8; ++i) {
            int k = i * 256 + c;
            WoT[(size_t)cc * 2048 + k] = __float2bfloat16(Wo[(size_t)k * 256 + cc]);
        }
    }
}

// ---------------------------------------------------------------------------
// attn: fused QKV projection (MFMA) + 8x8 head attention per token.
// Block = 64 tokens, 256 threads (4 waves), 1 block/CU.  Writes x_att to
// ws in natural [token][h*256+d] bf16 layout (scramble absorbed by outproj).
// LDS tiles are XOR-swizzled ((16B-group) ^ (row&7)) => conflict-free b128.
// ---------------------------------------------------------------------------
__global__ __launch_bounds__(256) void attn_kernel(
    const float* __restrict__ Qin, const float* __restrict__ Kin,
    const float* __restrict__ Vin, const int* __restrict__ mask,
    const bf16* __restrict__ WqT, const bf16* __restrict__ WkT,
    const bf16* __restrict__ WvT,
    const float* __restrict__ bqp, const float* __restrict__ bkp,
    const float* __restrict__ bvp,
    bf16* __restrict__ A)
{
    __shared__ __align__(16) char smem[131072];
    char* const XA = smem;            // [64][256] bf16 swizzled: Xq (ph1) / Xv (ph2)
    char* const XB = smem + 32768;    // [64][256] bf16: Xk (ph1) / x-stage XS (ph2)
    char* const WS = smem + 65536;    // [128][128] bf16: W^T half-K tile
    char* const QC = smem + 98304;    // [128 pl][64 t] bf16: q chunk
    char* const KC = smem + 114688;   // [128 pl][64 t] bf16: k chunk / v chunk
    char* const XS = XB;
    float* const RED = (float*)smem;  // [4][64 pair][64 t] fp32 score partials

    const int tid  = threadIdx.x;
    const int wave = tid >> 6;
    const int lane = tid & 63;
    const int quad = lane >> 4;
    const int l15  = lane & 15;
    const int tok0 = blockIdx.x * 64;

    auto stageX = [&](const float* src, char* dst) {
        #pragma unroll
        for (int it = 0; it < 8; ++it) {
            int p = tid + (it << 8);            // 2048 pieces: 64 rows x 32 groups
            int row = p >> 5, g = p & 31;
            const float* s = src + row * 256 + g * 8;
            float4 f0 = *(const float4*)s;
            float4 f1 = *(const float4*)(s + 4);
            union { unsigned short us[8]; uint4 v; } pk;
            pk.us[0] = f2us(f0.x); pk.us[1] = f2us(f0.y);
            pk.us[2] = f2us(f0.z); pk.us[3] = f2us(f0.w);
            pk.us[4] = f2us(f1.x); pk.us[5] = f2us(f1.y);
            pk.us[6] = f2us(f1.z); pk.us[7] = f2us(f1.w);
            *(uint4*)(dst + row * 512 + ((g ^ (row & 7)) << 4)) = pk.v;
        }
    };
    auto stageW = [&](const bf16* WT, int ch, int kh) {
        #pragma unroll
        for (int it = 0; it < 8; ++it) {
            int p = tid + (it << 8);            // 2048 pieces: 128 rows x 16 groups
            int pl = p >> 4, g = p & 15;
            uint4 v = *(const uint4*)(WT + ((size_t)(128 * ch + pl) << 8) + 128 * kh + g * 8);
            *(uint4*)(WS + pl * 256 + ((g ^ (pl & 7)) << 4)) = v;
        }
    };
    auto gemmHalf = [&](const char* Xb, int kh, f32x4 (&acc)[4][2]) {
        #pragma unroll
        for (int ks = 0; ks < 4; ++ks) {
            bf16x8 a[4], b[2];
            #pragma unroll
            for (int mt = 0; mt < 4; ++mt) {
                int row = mt * 16 + l15;
                int g = (16 * kh + 4 * ks + quad) ^ (row & 7);
                a[mt] = *(const bf16x8*)(Xb + row * 512 + (g << 4));
            }
            #pragma unroll
            for (int nt = 0; nt < 2; ++nt) {
                int pl = wave * 32 + nt * 16 + l15;
                int g = (4 * ks + quad) ^ (pl & 7);
                b[nt] = *(const bf16x8*)(WS + pl * 256 + (g << 4));
            }
            #pragma unroll
            for (int mt = 0; mt < 4; ++mt)
                #pragma unroll
                for (int nt = 0; nt < 2; ++nt)
                    acc[mt][nt] = MFMA16(a[mt], b[nt], acc[mt][nt]);
        }
    };
    auto writeC = [&](char* Cb, const float* biasp, int ch, f32x4 (&acc)[4][2]) {
        #pragma unroll
        for (int nt = 0; nt < 2; ++nt) {
            int pl = wave * 32 + nt * 16 + l15;
            float bias = biasp[128 * ch + pl];
            #pragma unroll
            for (int mt = 0; mt < 4; ++mt) {
                int t0 = mt * 16 + quad * 4;
                union { unsigned short us[4]; uint2 v; } pk;
                #pragma unroll
                for (int i = 0; i < 4; ++i) pk.us[i] = f2us(acc[mt][nt][i] + bias);
                *(uint2*)(Cb + pl * 128 + ((((t0 >> 3) ^ (pl & 7))) << 4) + (t0 & 7) * 2) = pk.v;
            }
        }
    };

    // ---- stage X tiles ----
    stageX(Qin + (size_t)tok0 * 256, XA);
    stageX(Kin + (size_t)tok0 * 256, XB);
    __syncthreads();

    float scp[64];
    #pragma unroll
    for (int i = 0; i < 64; ++i) scp[i] = 0.f;

    // ---- phase 1: q,k chunks + score accumulation (lane = token) ----
    for (int ch = 0; ch < NCH; ++ch) {
        f32x4 acc[4][2];
        #pragma unroll
        for (int mt = 0; mt < 4; ++mt)
            #pragma unroll
            for (int nt = 0; nt < 2; ++nt)
                #pragma unroll
                for (int i = 0; i < 4; ++i) acc[mt][nt][i] = 0.f;

        stageW(WqT, ch, 0); __syncthreads();
        gemmHalf(XA, 0, acc); __syncthreads();
        stageW(WqT, ch, 1); __syncthreads();
        gemmHalf(XA, 1, acc);
        writeC(QC, bqp, ch, acc); __syncthreads();

        #pragma unroll
        for (int mt = 0; mt < 4; ++mt)
            #pragma unroll
            for (int nt = 0; nt < 2; ++nt)
                #pragma unroll
                for (int i = 0; i < 4; ++i) acc[mt][nt][i] = 0.f;

        stageW(WkT, ch, 0); __syncthreads();
        gemmHalf(XB, 0, acc); __syncthreads();
        stageW(WkT, ch, 1); __syncthreads();
        gemmHalf(XB, 1, acc);
        writeC(KC, bkp, ch, acc); __syncthreads();

        // score: wave handles dl = 4*wave..4*wave+3 of this chunk's 16 d's
        #pragma unroll
        for (int d4 = 0; d4 < 4; ++d4) {
            int dl = wave * 4 + d4;
            float qv[8], kv[8];
            #pragma unroll
            for (int hh = 0; hh < 8; ++hh) {
                int pl = dl * 8 + hh;
                int off = pl * 128 + ((((lane >> 3) ^ (pl & 7))) << 4) + (lane & 7) * 2;
                qv[hh] = us2f(*(const unsigned short*)(QC + off));
                kv[hh] = us2f(*(const unsigned short*)(KC + off));
            }
            #pragma unroll
            for (int hh = 0; hh < 8; ++hh)
                #pragma unroll
                for (int g = 0; g < 8; ++g)
                    scp[hh * 8 + g] = fmaf(qv[hh], kv[g], scp[hh * 8 + g]);
        }
    }

    // ---- cross-wave score reduction + per-lane softmax (token = lane) ----
    __syncthreads();
    #pragma unroll
    for (int pr = 0; pr < 64; ++pr)
        RED[wave * 4096 + pr * 64 + lane] = scp[pr];
    __syncthreads();

    float wv[64];
    #pragma unroll
    for (int pr = 0; pr < 64; ++pr)
        wv[pr] = RED[pr * 64 + lane] + RED[4096 + pr * 64 + lane]
               + RED[8192 + pr * 64 + lane] + RED[12288 + pr * 64 + lane];
    {
        const int mk = mask[tok0 + lane];
        #pragma unroll
        for (int hh = 0; hh < 8; ++hh) {
            float m = wv[hh * 8];
            #pragma unroll
            for (int g = 1; g < 8; ++g) m = fmaxf(m, wv[hh * 8 + g]);
            float e[8], s = 0.f;
            #pragma unroll
            for (int g = 0; g < 8; ++g) { e[g] = __expf((wv[hh * 8 + g] - m) * 0.0625f); s += e[g]; }
            float inv = 1.f / s;
            #pragma unroll
            for (int g = 0; g < 8; ++g) wv[hh * 8 + g] = mk ? e[g] * inv : 0.125f;
        }
    }
    __syncthreads();
    stageX(Vin + (size_t)tok0 * 256, XA);   // Xv overwrites RED region
    __syncthreads();

    // ---- phase 2: v chunks + weighted sum + A write ----
    for (int ch = 0; ch < NCH; ++ch) {
        f32x4 acc[4][2];
        #pragma unroll
        for (int mt = 0; mt < 4; ++mt)
            #pragma unroll
            for (int nt = 0; nt < 2; ++nt)
                #pragma unroll
                for (int i = 0; i < 4; ++i) acc[mt][nt][i] = 0.f;

        stageW(WvT, ch, 0); __syncthreads();
        gemmHalf(XA, 0, acc); __syncthreads();
        stageW(WvT, ch, 1); __syncthreads();
        gemmHalf(XA, 1, acc);
        writeC(KC, bvp, ch, acc); __syncthreads();   // vc -> KC region

        float vvv[4][8];
        #pragma unroll
        for (int d4 = 0; d4 < 4; ++d4) {
            int dl = wave * 4 + d4;
            #pragma unroll
            for (int g = 0; g < 8; ++g) {
                int pl = dl * 8 + g;
                int off = pl * 128 + ((((lane >> 3) ^ (pl & 7))) << 4) + (lane & 7) * 2;
                vvv[d4][g] = us2f(*(const unsigned short*)(KC + off));
            }
        }
        #pragma unroll
        for (int hh = 0; hh < 8; ++hh) {
            union { unsigned short us[4]; uint2 v; } pk;
            #pragma unroll
            for (int d4 = 0; d4 < 4; ++d4) {
                float x = 0.f;
                #pragma unroll
                for (int g = 0; g < 8; ++g) x = fmaf(wv[hh * 8 + g], vvv[d4][g], x);
                pk.us[d4] = f2us(x);
            }
            int col0 = hh * 16 + wave * 4;
            *(uint2*)(XS + lane * 256 + ((((col0 >> 3) ^ (lane & 7))) << 4) + (col0 & 7) * 2) = pk.v;
        }
        __syncthreads();
        #pragma unroll
        for (int ii = 0; ii < 2; ++ii) {
            int sI = tid + (ii << 8);          // 512 segments: 64 t x 8 h
            int t = sI >> 3, hh = sI & 7;
            uint4 v0 = *(const uint4*)(XS + t * 256 + ((((hh * 2) ^ (t & 7))) << 4));
            uint4 v1 = *(const uint4*)(XS + t * 256 + ((((hh * 2 + 1) ^ (t & 7))) << 4));
            bf16* dst = A + ((size_t)(tok0 + t) << 11) + (hh << 8) + (ch << 4);
            *(uint4*)dst = v0;
            *(uint4*)(dst + 8) = v1;
        }
        // no trailing barrier needed: next XS writer is 4 barriers away
    }
}

// ---------------------------------------------------------------------------
// outproj: Out[16384][256] = A_scrambled @ Wo + bo, fp32 out.
// Scramble absorbed into A-tile gather: row r=(b,h,sg), k=(j,d) ->
// A_nat[t = b*2048 + sg*8 + j][h*256 + d].
// Block = 64 rows x 128 cols, grid 512.
// ---------------------------------------------------------------------------
__global__ __launch_bounds__(256) void outproj_kernel(
    const bf16* __restrict__ A, const bf16* __restrict__ WoT,
    const float* __restrict__ Wo, const float* __restrict__ bo,
    float* __restrict__ Out)
{
    __shared__ __align__(16) bf16 As[64][72];
    __shared__ __align__(16) bf16 Ws[128][72];
    const int tid  = threadIdx.x;
    const int wave = tid >> 6;
    const int lane = tid & 63;
    const int quad = lane >> 4;
    const int l15  = lane & 15;
    const int R = blockIdx.x >> 1, C = blockIdx.x & 1;

    f32x4 acc[4][2];
    #pragma unroll
    for (int mt = 0; mt < 4; ++mt)
        #pragma unroll
        for (int nt = 0; nt < 2; ++nt)
            #pragma unroll
            for (int i = 0; i < 4; ++i) acc[mt][nt][i] = 0.f;

    for (int kc = 0; kc < 32; ++kc) {
        const int j = kc >> 2, d0 = (kc & 3) * 64;
        // stage A tile (scramble gather), 512 pieces: 64 rows x 8 x 16B
        #pragma unroll
        for (int it = 0; it < 2; ++it) {
            int p = tid + (it << 8);
            int rho = p >> 3, kp = p & 7;
            int r = R * 64 + rho;
            int b = r >> 11, hh = (r >> 8) & 7, sg = r & 255;
            size_t t = ((size_t)b << 11) + sg * 8 + j;
            uint4 v = *(const uint4*)(A + (t << 11) + hh * 256 + d0 + kp * 8);
            *(uint4*)(&As[rho][kp * 8]) = v;
        }
        // stage Wo tile [c][k], 128 cols x 64 k
        if (WoT != nullptr) {
            #pragma unroll
            for (int it = 0; it < 4; ++it) {
                int p = tid + (it << 8);
                int cl = p >> 3, kp = p & 7;
                uint4 v = *(const uint4*)(WoT + ((size_t)(C * 128 + cl) << 11) + j * 256 + d0 + kp * 8);
                *(uint4*)(&Ws[cl][kp * 8]) = v;
            }
        } else {
            #pragma unroll
            for (int it = 0; it < 8; ++it) {
                int p = tid + (it << 8);
                int k = p >> 5, c4 = (p & 31) * 4;
                float4 f = *(const float4*)(Wo + (size_t)(j * 256 + d0 + k) * 256 + C * 128 + c4);
                Ws[c4 + 0][k] = __float2bfloat16(f.x);
                Ws[c4 + 1][k] = __float2bfloat16(f.y);
                Ws[c4 + 2][k] = __float2bfloat16(f.z);
                Ws[c4 + 3][k] = __float2bfloat16(f.w);
            }
        }
        __syncthreads();
        #pragma unroll
        for (int ks = 0; ks < 2; ++ks) {
            bf16x8 a[4], b[2];
            #pragma unroll
            for (int mt = 0; mt < 4; ++mt)
                a[mt] = *(const bf16x8*)(&As[mt * 16 + l15][ks * 32 + quad * 8]);
            #pragma unroll
            for (int nt = 0; nt < 2; ++nt)
                b[nt] = *(const bf16x8*)(&Ws[wave * 32 + nt * 16 + l15][ks * 32 + quad * 8]);
            #pragma unroll
            for (int mt = 0; mt < 4; ++mt)
                #pragma unroll
                for (int nt = 0; nt < 2; ++nt)
                    acc[mt][nt] = MFMA16(a[mt], b[nt], acc[mt][nt]);
        }
        __syncthreads();
    }
    #pragma unroll
    for (int nt = 0; nt < 2; ++nt) {
        int col = C * 128 + wave * 32 + nt * 16 + l15;
        float bias = bo[col];
        #pragma unroll
        for (int mt = 0; mt < 4; ++mt) {
            int row0 = R * 64 + mt * 16 + quad * 4;
            #pragma unroll
            for (int i = 0; i < 4; ++i)
                Out[(row0 + i) * 256 + col] = acc[mt][nt][i] + bias;
        }
    }
}

// ---------------------------------------------------------------------------
extern "C" void kernel_launch(void* const* d_in, const int* in_sizes, int n_in,
                              void* d_out, int out_size, void* d_ws, size_t ws_size,
                              hipStream_t stream) {
    const float* query = (const float*)d_in[0];
    const float* key   = (const float*)d_in[1];
    const float* value = (const float*)d_in[2];
    const int*   mask  = (const int*)  d_in[3];
    const float* Wq = (const float*)d_in[4];  const float* bq = (const float*)d_in[5];
    const float* Wk = (const float*)d_in[6];  const float* bk = (const float*)d_in[7];
    const float* Wv = (const float*)d_in[8];  const float* bv = (const float*)d_in[9];
    const float* Wo = (const float*)d_in[10]; const float* bo = (const float*)d_in[11];

    // prep region lives in d_out (consumed by attn before outproj overwrites)
    char* dc = (char*)d_out;
    bf16*  WqT = (bf16*)dc;                       // [2048][256]
    bf16*  WkT = WqT + 524288;
    bf16*  WvT = WkT + 524288;
    float* bqp = (float*)(dc + 3145728);
    float* bkp = bqp + 2048;
    float* bvp = bkp + 2048;

    bf16* A = (bf16*)d_ws;                        // [16384][2048] natural layout, 64 MB
    const bool big = ws_size >= (67108864ull + 1048576ull);
    bf16* WoT = big ? (bf16*)((char*)d_ws + 67108864) : nullptr;

    prep_kernel<<<big ? 2304 : 2048, 256, 0, stream>>>(
        Wq, Wk, Wv, bq, bk, bv, Wo, WqT, WkT, WvT, bqp, bkp, bvp, WoT);
    attn_kernel<<<256, 256, 0, stream>>>(
        query, key, value, mask, WqT, WkT, WvT, bqp, bkp, bvp, A);
    outproj_kernel<<<512, 256, 0, stream>>>(A, WoT, Wo, bo, (float*)d_out);
}

// Round 4
// 382.345 us; speedup vs baseline: 4.3726x; 1.1182x over previous
//
#include <hip/hip_runtime.h>
#include <hip/hip_bf16.h>

typedef __hip_bfloat16 bf16;
typedef short bf16x8 __attribute__((ext_vector_type(8)));
typedef float f32x4 __attribute__((ext_vector_type(4)));

#define MFMA16(a,b,c) __builtin_amdgcn_mfma_f32_16x16x32_bf16(a,b,c,0,0,0)

__device__ __forceinline__ unsigned short f2us(float x){
    union{__hip_bfloat16 h; unsigned short u;} c; c.h = __float2bfloat16(x); return c.u;
}
__device__ __forceinline__ float us2f(unsigned short u){
    union{unsigned short u; __hip_bfloat16 h;} c; c.u = u; return __bfloat162float(c.h);
}
__device__ __forceinline__ uint4 pack8(float4 a, float4 b){
    union{unsigned short us[8]; uint4 v;} p;
    p.us[0]=f2us(a.x); p.us[1]=f2us(a.y); p.us[2]=f2us(a.z); p.us[3]=f2us(a.w);
    p.us[4]=f2us(b.x); p.us[5]=f2us(b.y); p.us[6]=f2us(b.z); p.us[7]=f2us(b.w);
    return p.v;
}

// ---------------------------------------------------------------------------
// prep: LDS-tiled transposes.
//  blocks 0..383   : Wq/Wk/Wv [256][2048] fp32 -> WxT[p][c] bf16, p=d*8+h
//  blocks 384..386 : permuted biases
//  blocks 387..514 : Wo [2048][256] -> WoT[c][k] bf16 (only if big)
// ---------------------------------------------------------------------------
__global__ __launch_bounds__(256) void prep_kernel(
    const float* __restrict__ Wq, const float* __restrict__ Wk,
    const float* __restrict__ Wv, const float* __restrict__ bq,
    const float* __restrict__ bk, const float* __restrict__ bv,
    const float* __restrict__ Wo,
    bf16* __restrict__ WqT, bf16* __restrict__ WkT, bf16* __restrict__ WvT,
    float* __restrict__ bqp, float* __restrict__ bkp, float* __restrict__ bvp,
    bf16* __restrict__ WoT)
{
    __shared__ float T[64][68];
    const int tid = threadIdx.x, bx = blockIdx.x;
    if (bx < 384) {
        const int mat = bx / 128, rem = bx % 128;
        const int c0 = (rem >> 5) * 64, n0 = (rem & 31) * 64;
        const float* W = (mat == 0) ? Wq : (mat == 1) ? Wk : Wv;
        bf16* WT = (mat == 0) ? WqT : (mat == 1) ? WkT : WvT;
        #pragma unroll
        for (int it = 0; it < 4; ++it) {
            int pp = tid + (it << 8);
            int cl = pp >> 4, n4 = (pp & 15) * 4;
            float4 f = *(const float4*)(W + (size_t)(c0 + cl) * 2048 + n0 + n4);
            T[cl][n4] = f.x; T[cl][n4+1] = f.y; T[cl][n4+2] = f.z; T[cl][n4+3] = f.w;
        }
        __syncthreads();
        const int h = n0 >> 8, d0 = n0 & 255;
        #pragma unroll
        for (int it = 0; it < 2; ++it) {
            int pp = tid + (it << 8);
            int j = pp >> 3, g = pp & 7;
            union{unsigned short us[8]; uint4 v;} pk;
            #pragma unroll
            for (int u = 0; u < 8; ++u) pk.us[u] = f2us(T[g*8+u][j]);
            *(uint4*)(WT + (size_t)((d0 + j) * 8 + h) * 256 + c0 + g * 8) = pk.v;
        }
    } else if (bx < 387) {
        const int mat = bx - 384;
        const float* src = (mat == 0) ? bq : (mat == 1) ? bk : bv;
        float* dst = (mat == 0) ? bqp : (mat == 1) ? bkp : bvp;
        for (int n = tid; n < 2048; n += 256)
            dst[(n & 255) * 8 + (n >> 8)] = src[n];
    } else {
        const int idx = bx - 387;
        const int k0 = (idx >> 2) * 64, c0 = (idx & 3) * 64;
        #pragma unroll
        for (int it = 0; it < 4; ++it) {
            int pp = tid + (it << 8);
            int kl = pp >> 4, c4 = (pp & 15) * 4;
            float4 f = *(const float4*)(Wo + (size_t)(k0 + kl) * 256 + c0 + c4);
            T[kl][c4] = f.x; T[kl][c4+1] = f.y; T[kl][c4+2] = f.z; T[kl][c4+3] = f.w;
        }
        __syncthreads();
        #pragma unroll
        for (int it = 0; it < 2; ++it) {
            int pp = tid + (it << 8);
            int j = pp >> 3, g = pp & 7;   // j = c-local, g = k-group
            union{unsigned short us[8]; uint4 v;} pk;
            #pragma unroll
            for (int u = 0; u < 8; ++u) pk.us[u] = f2us(T[g*8+u][j]);
            *(uint4*)(WoT + (size_t)(c0 + j) * 2048 + k0 + g * 8) = pk.v;
        }
    }
}

// ---------------------------------------------------------------------------
// qk_softmax: block = 32 tokens. X staged once (persistent LDS, swizzled).
// Loops 16 column-chunks (128 permuted cols = 16 d x 8 heads): dual Q/K MFMA,
// per-token 8x8 score partials accumulate in registers; final cross-group
// reduce + softmax -> w[16384][64] fp32.
// ---------------------------------------------------------------------------
__global__ __launch_bounds__(256) void qk_softmax_kernel(
    const float* __restrict__ Qin, const float* __restrict__ Kin,
    const int* __restrict__ mask,
    const bf16* __restrict__ WqT, const bf16* __restrict__ WkT,
    const float* __restrict__ bqp, const float* __restrict__ bkp,
    float* __restrict__ w)
{
    __shared__ __align__(16) char smem[65536];
    char* const XqP = smem;            // [32][256] bf16 swizzled (16 KB)
    char* const XkP = smem + 16384;    // 16 KB
    char* const WqS = smem + 32768;    // [128][64] bf16 swizzled (16 KB)
    char* const WkS = smem + 49152;    // 16 KB
    char* const QT  = smem + 32768;    // [128 p][36 t] bf16 (9216) alias WqS
    char* const KT  = smem + 41984;    // 9216
    float* const RED = (float*)(smem + 51200);  // [32][64] fp32 (8 KB)

    const int tid = threadIdx.x;
    const int wave = tid >> 6, lane = tid & 63, quad = lane >> 4, l15 = lane & 15;
    const int tok0 = blockIdx.x * 32;
    const int tloc = tid & 31, dg = tid >> 5;   // dg = 0..7: 2 d's each

    // persistent X stage (both matrices), fp32 -> bf16, XOR-swizzled 16B groups
    #pragma unroll
    for (int it = 0; it < 4; ++it) {
        int pp = tid + (it << 8);
        int row = pp >> 5, g = pp & 31;
        const float* s = Qin + (size_t)(tok0 + row) * 256 + g * 8;
        *(uint4*)(XqP + row * 512 + ((g ^ (row & 7)) << 4)) =
            pack8(*(const float4*)s, *(const float4*)(s + 4));
        s = Kin + (size_t)(tok0 + row) * 256 + g * 8;
        *(uint4*)(XkP + row * 512 + ((g ^ (row & 7)) << 4)) =
            pack8(*(const float4*)s, *(const float4*)(s + 4));
    }

    float s_[64];
    #pragma unroll
    for (int i = 0; i < 64; ++i) s_[i] = 0.f;

    for (int C = 0; C < 16; ++C) {
        f32x4 accq[2][2], acck[2][2];
        #pragma unroll
        for (int mt = 0; mt < 2; ++mt)
            #pragma unroll
            for (int nt = 0; nt < 2; ++nt)
                #pragma unroll
                for (int i = 0; i < 4; ++i) { accq[mt][nt][i] = 0.f; acck[mt][nt][i] = 0.f; }

        for (int kc = 0; kc < 4; ++kc) {
            __syncthreads();   // protects prev MFMA frag reads / prev-C QT,KT reads
            #pragma unroll
            for (int it = 0; it < 4; ++it) {
                int pp = tid + (it << 8);
                int pl = pp >> 3, g = pp & 7;
                *(uint4*)(WqS + pl * 128 + ((g ^ (pl & 7)) << 4)) =
                    *(const uint4*)(WqT + (size_t)(C * 128 + pl) * 256 + kc * 64 + g * 8);
                *(uint4*)(WkS + pl * 128 + ((g ^ (pl & 7)) << 4)) =
                    *(const uint4*)(WkT + (size_t)(C * 128 + pl) * 256 + kc * 64 + g * 8);
            }
            __syncthreads();
            #pragma unroll
            for (int ks = 0; ks < 2; ++ks) {
                bf16x8 aq[2], ak[2], bq2[2], bk2[2];
                #pragma unroll
                for (int mt = 0; mt < 2; ++mt) {
                    int row = mt * 16 + l15;
                    int G = (kc * 8 + ks * 4 + quad) ^ (row & 7);
                    aq[mt] = *(const bf16x8*)(XqP + row * 512 + (G << 4));
                    ak[mt] = *(const bf16x8*)(XkP + row * 512 + (G << 4));
                }
                #pragma unroll
                for (int nt = 0; nt < 2; ++nt) {
                    int pl = wave * 32 + nt * 16 + l15;
                    int G = (ks * 4 + quad) ^ (pl & 7);
                    bq2[nt] = *(const bf16x8*)(WqS + pl * 128 + (G << 4));
                    bk2[nt] = *(const bf16x8*)(WkS + pl * 128 + (G << 4));
                }
                #pragma unroll
                for (int mt = 0; mt < 2; ++mt)
                    #pragma unroll
                    for (int nt = 0; nt < 2; ++nt) {
                        accq[mt][nt] = MFMA16(aq[mt], bq2[nt], accq[mt][nt]);
                        acck[mt][nt] = MFMA16(ak[mt], bk2[nt], acck[mt][nt]);
                    }
            }
        }
        __syncthreads();   // MFMA done -> safe to overwrite W region with QT/KT
        #pragma unroll
        for (int nt = 0; nt < 2; ++nt) {
            int pl = wave * 32 + nt * 16 + l15;
            float biq = bqp[C * 128 + pl], bik = bkp[C * 128 + pl];
            #pragma unroll
            for (int mt = 0; mt < 2; ++mt) {
                int t0 = mt * 16 + quad * 4;
                union{unsigned short us[4]; uint2 v;} pq, pk;
                #pragma unroll
                for (int i = 0; i < 4; ++i) {
                    pq.us[i] = f2us(accq[mt][nt][i] + biq);
                    pk.us[i] = f2us(acck[mt][nt][i] + bik);
                }
                *(uint2*)(QT + pl * 72 + t0 * 2) = pq.v;
                *(uint2*)(KT + pl * 72 + t0 * 2) = pk.v;
            }
        }
        __syncthreads();
        // score partials: thread (tloc, dg) covers d_local = dg*2 + {0,1}
        #pragma unroll
        for (int dd = 0; dd < 2; ++dd) {
            int d = dg * 2 + dd;
            float qv[8], kv[8];
            #pragma unroll
            for (int h = 0; h < 8; ++h) {
                qv[h] = us2f(*(const unsigned short*)(QT + (d * 8 + h) * 72 + tloc * 2));
                kv[h] = us2f(*(const unsigned short*)(KT + (d * 8 + h) * 72 + tloc * 2));
            }
            #pragma unroll
            for (int h = 0; h < 8; ++h)
                #pragma unroll
                for (int g = 0; g < 8; ++g)
                    s_[h * 8 + g] = fmaf(qv[h], kv[g], s_[h * 8 + g]);
        }
        // next C's kc-top sync protects QT/KT before restaging
    }

    __syncthreads();
    if (dg == 0) {
        #pragma unroll
        for (int j = 0; j < 64; ++j) RED[tloc * 64 + j] = s_[j];
    }
    __syncthreads();
    if (dg != 0) {
        #pragma unroll
        for (int j = 0; j < 64; ++j) atomicAdd(&RED[tloc * 64 + j], s_[j]);
    }
    __syncthreads();
    if (dg == 0) {
        const int mk = mask[tok0 + tloc];
        float o[64];
        #pragma unroll
        for (int h = 0; h < 8; ++h) {
            float m = RED[tloc * 64 + h * 8];
            #pragma unroll
            for (int g = 1; g < 8; ++g) m = fmaxf(m, RED[tloc * 64 + h * 8 + g]);
            float e[8], sum = 0.f;
            #pragma unroll
            for (int g = 0; g < 8; ++g) {
                e[g] = __expf((RED[tloc * 64 + h * 8 + g] - m) * 0.0625f);
                sum += e[g];
            }
            float inv = 1.f / sum;
            #pragma unroll
            for (int g = 0; g < 8; ++g) o[h * 8 + g] = mk ? e[g] * inv : 0.125f;
        }
        float* wp = w + (size_t)(tok0 + tloc) * 64;
        #pragma unroll
        for (int i = 0; i < 16; ++i) ((float4*)wp)[i] = ((float4*)o)[i];
    }
}

// ---------------------------------------------------------------------------
// v_attn: block = 32 tokens, Xv persistent; per chunk: V-GEMM (MFMA) ->
// attention weighted sum (w in registers) -> x written in SCRAMBLED layout
// A[r = b*2048 + h*256 + sg][col = j*256 + d]  (t = b*2048 + sg*8 + j).
// ---------------------------------------------------------------------------
__global__ __launch_bounds__(256) void v_attn_kernel(
    const float* __restrict__ Vin,
    const bf16* __restrict__ WvT, const float* __restrict__ bvp,
    const float* __restrict__ w, bf16* __restrict__ A)
{
    __shared__ __align__(16) char smem[40960];
    char* const XvP = smem;            // [32][256] bf16 swizzled (16 KB)
    char* const WvS = smem + 16384;    // [128][64] bf16 swizzled (16 KB)
    char* const VT  = smem + 16384;    // [128 p][36 t] bf16 (9216) alias WvS
    char* const xS  = smem + 32768;    // [32 t][8 h][16 d] bf16 (8 KB)

    const int tid = threadIdx.x;
    const int wave = tid >> 6, lane = tid & 63, quad = lane >> 4, l15 = lane & 15;
    const int tok0 = blockIdx.x * 32;
    const int tloc = tid & 31, dg = tid >> 5;

    #pragma unroll
    for (int it = 0; it < 4; ++it) {
        int pp = tid + (it << 8);
        int row = pp >> 5, g = pp & 31;
        const float* s = Vin + (size_t)(tok0 + row) * 256 + g * 8;
        *(uint4*)(XvP + row * 512 + ((g ^ (row & 7)) << 4)) =
            pack8(*(const float4*)s, *(const float4*)(s + 4));
    }
    // attention weights for this thread's token (redundant across dg, loaded once)
    float wv[64];
    {
        const float* wp = w + (size_t)(tok0 + tloc) * 64;
        #pragma unroll
        for (int i = 0; i < 16; ++i) {
            float4 f = ((const float4*)wp)[i];
            wv[i*4] = f.x; wv[i*4+1] = f.y; wv[i*4+2] = f.z; wv[i*4+3] = f.w;
        }
    }

    for (int C = 0; C < 16; ++C) {
        f32x4 acc[2][2];
        #pragma unroll
        for (int mt = 0; mt < 2; ++mt)
            #pragma unroll
            for (int nt = 0; nt < 2; ++nt)
                #pragma unroll
                for (int i = 0; i < 4; ++i) acc[mt][nt][i] = 0.f;

        for (int kc = 0; kc < 4; ++kc) {
            __syncthreads();
            #pragma unroll
            for (int it = 0; it < 4; ++it) {
                int pp = tid + (it << 8);
                int pl = pp >> 3, g = pp & 7;
                *(uint4*)(WvS + pl * 128 + ((g ^ (pl & 7)) << 4)) =
                    *(const uint4*)(WvT + (size_t)(C * 128 + pl) * 256 + kc * 64 + g * 8);
            }
            __syncthreads();
            #pragma unroll
            for (int ks = 0; ks < 2; ++ks) {
                bf16x8 a[2], b[2];
                #pragma unroll
                for (int mt = 0; mt < 2; ++mt) {
                    int row = mt * 16 + l15;
                    int G = (kc * 8 + ks * 4 + quad) ^ (row & 7);
                    a[mt] = *(const bf16x8*)(XvP + row * 512 + (G << 4));
                }
                #pragma unroll
                for (int nt = 0; nt < 2; ++nt) {
                    int pl = wave * 32 + nt * 16 + l15;
                    int G = (ks * 4 + quad) ^ (pl & 7);
                    b[nt] = *(const bf16x8*)(WvS + pl * 128 + (G << 4));
                }
                #pragma unroll
                for (int mt = 0; mt < 2; ++mt)
                    #pragma unroll
                    for (int nt = 0; nt < 2; ++nt)
                        acc[mt][nt] = MFMA16(a[mt], b[nt], acc[mt][nt]);
            }
        }
        __syncthreads();
        #pragma unroll
        for (int nt = 0; nt < 2; ++nt) {
            int pl = wave * 32 + nt * 16 + l15;
            float biv = bvp[C * 128 + pl];
            #pragma unroll
            for (int mt = 0; mt < 2; ++mt) {
                int t0 = mt * 16 + quad * 4;
                union{unsigned short us[4]; uint2 v;} pk;
                #pragma unroll
                for (int i = 0; i < 4; ++i) pk.us[i] = f2us(acc[mt][nt][i] + biv);
                *(uint2*)(VT + pl * 72 + t0 * 2) = pk.v;
            }
        }
        __syncthreads();
        // weighted sum: thread (tloc, dg) covers d_local = dg*2 + {0,1}
        #pragma unroll
        for (int dd = 0; dd < 2; ++dd) {
            int d = dg * 2 + dd;
            float vv[8];
            #pragma unroll
            for (int g = 0; g < 8; ++g)
                vv[g] = us2f(*(const unsigned short*)(VT + (d * 8 + g) * 72 + tloc * 2));
            #pragma unroll
            for (int h = 0; h < 8; ++h) {
                float x = 0.f;
                #pragma unroll
                for (int g = 0; g < 8; ++g) x = fmaf(wv[h * 8 + g], vv[g], x);
                *(unsigned short*)(xS + tloc * 256 + h * 32 + d * 2) = f2us(x);
            }
        }
        __syncthreads();
        // cooperative 32B-segment scrambled store
        {
            int t = tid >> 3, hh = tid & 7;
            int tok = tok0 + t;
            int b = tok >> 11, sr = tok & 2047, sg = sr >> 3, j = sr & 7;
            size_t r = ((size_t)b << 11) + hh * 256 + sg;
            bf16* dst = A + r * 2048 + j * 256 + C * 16;
            uint4 v0 = *(const uint4*)(xS + t * 256 + hh * 32);
            uint4 v1 = *(const uint4*)(xS + t * 256 + hh * 32 + 16);
            *(uint4*)dst = v0;
            *(uint4*)(dst + 8) = v1;
        }
    }
}

// ---------------------------------------------------------------------------
// outproj: plain GEMM Out[16384][256] = A_scr @ Wo + bo (fp32 out).
// Grid 512: R = M-tile(64) 0..255, C = N-tile(128) 0..1. K=2048, BK=64.
// ---------------------------------------------------------------------------
__global__ __launch_bounds__(256) void outproj_kernel(
    const bf16* __restrict__ A, const bf16* __restrict__ WoT,
    const float* __restrict__ Wo, const float* __restrict__ bo,
    float* __restrict__ Out)
{
    __shared__ __align__(16) char smem[24576];
    char* const AsS = smem;            // [64][64] bf16 swizzled (8 KB)
    char* const Ws  = smem + 8192;     // [128][64] bf16 swizzled (16 KB)

    const int tid = threadIdx.x;
    const int wave = tid >> 6, lane = tid & 63, quad = lane >> 4, l15 = lane & 15;
    const int R = blockIdx.x >> 1, C = blockIdx.x & 1;
    const int row0 = R * 64, col0 = C * 128;

    f32x4 acc[4][2];
    #pragma unroll
    for (int mt = 0; mt < 4; ++mt)
        #pragma unroll
        for (int nt = 0; nt < 2; ++nt)
            #pragma unroll
            for (int i = 0; i < 4; ++i) acc[mt][nt][i] = 0.f;

    for (int kc = 0; kc < 32; ++kc) {
        __syncthreads();
        #pragma unroll
        for (int it = 0; it < 2; ++it) {
            int pp = tid + (it << 8);
            int rho = pp >> 3, g = pp & 7;
            *(uint4*)(AsS + rho * 128 + ((g ^ (rho & 7)) << 4)) =
                *(const uint4*)(A + (size_t)(row0 + rho) * 2048 + kc * 64 + g * 8);
        }
        if (WoT != nullptr) {
            #pragma unroll
            for (int it = 0; it < 4; ++it) {
                int pp = tid + (it << 8);
                int cl = pp >> 3, g = pp & 7;
                *(uint4*)(Ws + cl * 128 + ((g ^ (cl & 7)) << 4)) =
                    *(const uint4*)(WoT + (size_t)(col0 + cl) * 2048 + kc * 64 + g * 8);
            }
        } else {
            #pragma unroll
            for (int it = 0; it < 8; ++it) {
                int pp = tid + (it << 8);
                int kl = pp >> 5, c4 = (pp & 31) * 4;
                float4 f = *(const float4*)(Wo + (size_t)(kc * 64 + kl) * 256 + col0 + c4);
                float fv[4] = {f.x, f.y, f.z, f.w};
                #pragma unroll
                for (int u = 0; u < 4; ++u) {
                    int cl = c4 + u;
                    *(unsigned short*)(Ws + cl * 128 + (((kl >> 3) ^ (cl & 7)) << 4) + (kl & 7) * 2)
                        = f2us(fv[u]);
                }
            }
        }
        __syncthreads();
        #pragma unroll
        for (int ks = 0; ks < 2; ++ks) {
            bf16x8 a[4], b[2];
            #pragma unroll
            for (int mt = 0; mt < 4; ++mt) {
                int row = mt * 16 + l15;
                int G = (ks * 4 + quad) ^ (row & 7);
                a[mt] = *(const bf16x8*)(AsS + row * 128 + (G << 4));
            }
            #pragma unroll
            for (int nt = 0; nt < 2; ++nt) {
                int cl = wave * 32 + nt * 16 + l15;
                int G = (ks * 4 + quad) ^ (cl & 7);
                b[nt] = *(const bf16x8*)(Ws + cl * 128 + (G << 4));
            }
            #pragma unroll
            for (int mt = 0; mt < 4; ++mt)
                #pragma unroll
                for (int nt = 0; nt < 2; ++nt)
                    acc[mt][nt] = MFMA16(a[mt], b[nt], acc[mt][nt]);
        }
    }
    #pragma unroll
    for (int nt = 0; nt < 2; ++nt) {
        int col = col0 + wave * 32 + nt * 16 + l15;
        float bias = bo[col];
        #pragma unroll
        for (int mt = 0; mt < 4; ++mt) {
            int r0 = row0 + mt * 16 + quad * 4;
            #pragma unroll
            for (int i = 0; i < 4; ++i)
                Out[(size_t)(r0 + i) * 256 + col] = acc[mt][nt][i] + bias;
        }
    }
}

// ---------------------------------------------------------------------------
extern "C" void kernel_launch(void* const* d_in, const int* in_sizes, int n_in,
                              void* d_out, int out_size, void* d_ws, size_t ws_size,
                              hipStream_t stream) {
    const float* query = (const float*)d_in[0];
    const float* key   = (const float*)d_in[1];
    const float* value = (const float*)d_in[2];
    const int*   mask  = (const int*)  d_in[3];
    const float* Wq = (const float*)d_in[4];  const float* bq = (const float*)d_in[5];
    const float* Wk = (const float*)d_in[6];  const float* bk = (const float*)d_in[7];
    const float* Wv = (const float*)d_in[8];  const float* bv = (const float*)d_in[9];
    const float* Wo = (const float*)d_in[10]; const float* bo = (const float*)d_in[11];

    // d_out doubles as scratch; everything here is consumed before outproj
    // overwrites d_out with the real output.
    char* dc = (char*)d_out;
    bf16*  WqT = (bf16*)dc;                    // [2048][256] bf16, 1 MB
    bf16*  WkT = (bf16*)(dc + 1048576);
    bf16*  WvT = (bf16*)(dc + 2097152);
    float* bqp = (float*)(dc + 3145728);
    float* bkp = (float*)(dc + 3153920);
    float* bvp = (float*)(dc + 3162112);
    float* w   = (float*)(dc + 3170304);       // [16384][64] fp32, 4 MB

    bf16* A = (bf16*)d_ws;                     // scrambled x_att, 64 MB
    const bool big = ws_size >= (67108864ull + 1048576ull);
    bf16* WoT = big ? (bf16*)((char*)d_ws + 67108864) : nullptr;

    prep_kernel<<<big ? 515 : 387, 256, 0, stream>>>(
        Wq, Wk, Wv, bq, bk, bv, Wo, WqT, WkT, WvT, bqp, bkp, bvp, WoT);
    qk_softmax_kernel<<<512, 256, 0, stream>>>(
        query, key, mask, WqT, WkT, bqp, bkp, w);
    v_attn_kernel<<<512, 256, 0, stream>>>(value, WvT, bvp, w, A);
    outproj_kernel<<<512, 256, 0, stream>>>(A, WoT, Wo, bo, (float*)d_out);
}

// Round 5
// 305.721 us; speedup vs baseline: 5.4685x; 1.2506x over previous
//
#include <hip/hip_runtime.h>
#include <hip/hip_bf16.h>

typedef __hip_bfloat16 bf16;
typedef short bf16x8 __attribute__((ext_vector_type(8)));
typedef float f32x4 __attribute__((ext_vector_type(4)));

#define MFMA16(a,b,c) __builtin_amdgcn_mfma_f32_16x16x32_bf16(a,b,c,0,0,0)

__device__ __forceinline__ unsigned short f2us(float x){
    union{__hip_bfloat16 h; unsigned short u;} c; c.h = __float2bfloat16(x); return c.u;
}
__device__ __forceinline__ float us2f(unsigned short u){
    union{unsigned short u; __hip_bfloat16 h;} c; c.u = u; return __bfloat162float(c.h);
}
__device__ __forceinline__ uint4 pack8(float4 a, float4 b){
    union{unsigned short us[8]; uint4 v;} p;
    p.us[0]=f2us(a.x); p.us[1]=f2us(a.y); p.us[2]=f2us(a.z); p.us[3]=f2us(a.w);
    p.us[4]=f2us(b.x); p.us[5]=f2us(b.y); p.us[6]=f2us(b.z); p.us[7]=f2us(b.w);
    return p.v;
}

// ---------------------------------------------------------------------------
// prep: LDS-tiled transposes (unchanged from R4).
// ---------------------------------------------------------------------------
__global__ __launch_bounds__(256) void prep_kernel(
    const float* __restrict__ Wq, const float* __restrict__ Wk,
    const float* __restrict__ Wv, const float* __restrict__ bq,
    const float* __restrict__ bk, const float* __restrict__ bv,
    const float* __restrict__ Wo,
    bf16* __restrict__ WqT, bf16* __restrict__ WkT, bf16* __restrict__ WvT,
    float* __restrict__ bqp, float* __restrict__ bkp, float* __restrict__ bvp,
    bf16* __restrict__ WoT)
{
    __shared__ float T[64][68];
    const int tid = threadIdx.x, bx = blockIdx.x;
    if (bx < 384) {
        const int mat = bx / 128, rem = bx % 128;
        const int c0 = (rem >> 5) * 64, n0 = (rem & 31) * 64;
        const float* W = (mat == 0) ? Wq : (mat == 1) ? Wk : Wv;
        bf16* WT = (mat == 0) ? WqT : (mat == 1) ? WkT : WvT;
        #pragma unroll
        for (int it = 0; it < 4; ++it) {
            int pp = tid + (it << 8);
            int cl = pp >> 4, n4 = (pp & 15) * 4;
            float4 f = *(const float4*)(W + (size_t)(c0 + cl) * 2048 + n0 + n4);
            T[cl][n4] = f.x; T[cl][n4+1] = f.y; T[cl][n4+2] = f.z; T[cl][n4+3] = f.w;
        }
        __syncthreads();
        const int h = n0 >> 8, d0 = n0 & 255;
        #pragma unroll
        for (int it = 0; it < 2; ++it) {
            int pp = tid + (it << 8);
            int j = pp >> 3, g = pp & 7;
            union{unsigned short us[8]; uint4 v;} pk;
            #pragma unroll
            for (int u = 0; u < 8; ++u) pk.us[u] = f2us(T[g*8+u][j]);
            *(uint4*)(WT + (size_t)((d0 + j) * 8 + h) * 256 + c0 + g * 8) = pk.v;
        }
    } else if (bx < 387) {
        const int mat = bx - 384;
        const float* src = (mat == 0) ? bq : (mat == 1) ? bk : bv;
        float* dst = (mat == 0) ? bqp : (mat == 1) ? bkp : bvp;
        for (int n = tid; n < 2048; n += 256)
            dst[(n & 255) * 8 + (n >> 8)] = src[n];
    } else {
        const int idx = bx - 387;
        const int k0 = (idx >> 2) * 64, c0 = (idx & 3) * 64;
        #pragma unroll
        for (int it = 0; it < 4; ++it) {
            int pp = tid + (it << 8);
            int kl = pp >> 4, c4 = (pp & 15) * 4;
            float4 f = *(const float4*)(Wo + (size_t)(k0 + kl) * 256 + c0 + c4);
            T[kl][c4] = f.x; T[kl][c4+1] = f.y; T[kl][c4+2] = f.z; T[kl][c4+3] = f.w;
        }
        __syncthreads();
        #pragma unroll
        for (int it = 0; it < 2; ++it) {
            int pp = tid + (it << 8);
            int j = pp >> 3, g = pp & 7;
            union{unsigned short us[8]; uint4 v;} pk;
            #pragma unroll
            for (int u = 0; u < 8; ++u) pk.us[u] = f2us(T[g*8+u][j]);
            *(uint4*)(WoT + (size_t)(c0 + j) * 2048 + k0 + g * 8) = pk.v;
        }
    }
}

// ---------------------------------------------------------------------------
// qk: 64 tokens/block, 512 threads, grid 256. Waves own 16-col slices;
// B-frags straight from global (WqT/WkT pre-transposed). Q/K chunk results
// round-trip LDS once; scores accumulate via block-diagonal pair-MFMA.
// 2 barriers per chunk-pair. Softmax -> w[16384][64].
// ---------------------------------------------------------------------------
__global__ __launch_bounds__(512) void qk_kernel(
    const float* __restrict__ Qin, const float* __restrict__ Kin,
    const int* __restrict__ mask,
    const bf16* __restrict__ WqT, const bf16* __restrict__ WkT,
    const float* __restrict__ bqp, const float* __restrict__ bkp,
    float* __restrict__ w)
{
    __shared__ __align__(16) char smem[147456];
    char* const Xq = smem;             // [64][256] bf16 swizzled (32 KB)
    char* const Xk = smem + 32768;     // 32 KB
    char* const QT = smem + 65536;     // [256 p2][pitch 160B] (40 KB)
    char* const KT = smem + 106496;    // 40 KB
    float* const RED = (float*)smem;   // [64][68] fp32 alias over Xq

    const int tid  = threadIdx.x;
    const int wid  = tid >> 6, lane = tid & 63;
    const int quad = lane >> 4, l15 = lane & 15;
    const int tok0 = blockIdx.x * 64;

    // stage Xq, Xk once (fp32 -> bf16, XOR-swizzled 16B groups)
    #pragma unroll
    for (int it = 0; it < 4; ++it) {
        int pp = tid + (it << 9);
        int row = pp >> 5, g = pp & 31;
        const float* s = Qin + (size_t)(tok0 + row) * 256 + g * 8;
        *(uint4*)(Xq + row * 512 + ((g ^ (row & 7)) << 4)) =
            pack8(*(const float4*)s, *(const float4*)(s + 4));
        s = Kin + (size_t)(tok0 + row) * 256 + g * 8;
        *(uint4*)(Xk + row * 512 + ((g ^ (row & 7)) << 4)) =
            pack8(*(const float4*)s, *(const float4*)(s + 4));
    }
    __syncthreads();

    f32x4 sacc[4];
    #pragma unroll
    for (int p = 0; p < 4; ++p)
        #pragma unroll
        for (int i = 0; i < 4; ++i) sacc[p][i] = 0.f;

    const int pll = wid * 16 + l15;    // block-local column 0..127

    for (int Cp = 0; Cp < 8; ++Cp) {
        #pragma unroll
        for (int par = 0; par < 2; ++par) {
            const int C = Cp * 2 + par;
            f32x4 accq[4], acck[4];
            #pragma unroll
            for (int mt = 0; mt < 4; ++mt)
                #pragma unroll
                for (int i = 0; i < 4; ++i) { accq[mt][i] = 0.f; acck[mt][i] = 0.f; }
            #pragma unroll
            for (int Ks = 0; Ks < 8; ++Ks) {
                bf16x8 bq = *(const bf16x8*)(WqT + (size_t)(C * 128 + pll) * 256 + Ks * 32 + quad * 8);
                bf16x8 bk = *(const bf16x8*)(WkT + (size_t)(C * 128 + pll) * 256 + Ks * 32 + quad * 8);
                #pragma unroll
                for (int mt = 0; mt < 4; ++mt) {
                    int row = mt * 16 + l15;
                    int G = (Ks * 4 + quad) ^ (row & 7);
                    bf16x8 a = *(const bf16x8*)(Xq + row * 512 + (G << 4));
                    accq[mt] = MFMA16(a, bq, accq[mt]);
                    a = *(const bf16x8*)(Xk + row * 512 + (G << 4));
                    acck[mt] = MFMA16(a, bk, acck[mt]);
                }
            }
            const int p2 = par * 128 + pll;
            const int rowoff = p2 * 160 + ((p2 >> 6) & 3) * 8;
            const float biq = bqp[C * 128 + pll];
            const float bik = bkp[C * 128 + pll];
            #pragma unroll
            for (int mt = 0; mt < 4; ++mt) {
                int t0 = mt * 16 + quad * 4;
                union{unsigned short us[4]; uint2 v;} pq, pk;
                #pragma unroll
                for (int i = 0; i < 4; ++i) {
                    pq.us[i] = f2us(accq[mt][i] + biq);
                    pk.us[i] = f2us(acck[mt][i] + bik);
                }
                *(uint2*)(QT + rowoff + t0 * 2) = pq.v;
                *(uint2*)(KT + rowoff + t0 * 2) = pk.v;
            }
        }
        __syncthreads();
        // block-diagonal score MFMA: 4 token-pairs per wave
        #pragma unroll
        for (int pp2 = 0; pp2 < 4; ++pp2) {
            int tq = 2 * (wid * 4 + pp2) + (l15 >> 3);
            union{unsigned short us[8]; bf16x8 v;} Aq, Bk;
            #pragma unroll
            for (int j = 0; j < 8; ++j) {
                int p2 = (quad * 8 + j) * 8 + (l15 & 7);
                int off = p2 * 160 + ((p2 >> 6) & 3) * 8 + tq * 2;
                Aq.us[j] = *(const unsigned short*)(QT + off);
                Bk.us[j] = *(const unsigned short*)(KT + off);
            }
            sacc[pp2] = MFMA16(Aq.v, Bk.v, sacc[pp2]);
        }
        __syncthreads();
    }

    // diagonal extraction -> RED[t][h*8+g]
    if ((quad >> 1) == (l15 >> 3)) {
        #pragma unroll
        for (int pp2 = 0; pp2 < 4; ++pp2) {
            int tl = (wid * 4 + pp2) * 2 + (l15 >> 3);
            #pragma unroll
            for (int i = 0; i < 4; ++i)
                RED[tl * 68 + ((quad & 1) * 4 + i) * 8 + (l15 & 7)] = sacc[pp2][i];
        }
    }
    __syncthreads();
    // softmax: thread (tl, h)
    {
        const int tl = tid >> 3, hh = tid & 7;
        const int mk = mask[tok0 + tl];
        const float* r = RED + tl * 68 + hh * 8;
        float m = r[0];
        #pragma unroll
        for (int g = 1; g < 8; ++g) m = fmaxf(m, r[g]);
        float e[8], sum = 0.f;
        #pragma unroll
        for (int g = 0; g < 8; ++g) { e[g] = __expf((r[g] - m) * 0.0625f); sum += e[g]; }
        float inv = 1.f / sum;
        float o[8];
        #pragma unroll
        for (int g = 0; g < 8; ++g) o[g] = mk ? e[g] * inv : 0.125f;
        float* wp = w + (size_t)(tok0 + tl) * 64 + hh * 8;
        *(float4*)wp = make_float4(o[0], o[1], o[2], o[3]);
        *(float4*)(wp + 4) = make_float4(o[4], o[5], o[6], o[7]);
    }
}

// ---------------------------------------------------------------------------
// v_attn: 64 tokens/block, 512 threads, grid 256. V-proj with direct-global
// B-frags, VT round-trip, VALU weighted sum (w in regs), scrambled A store.
// ---------------------------------------------------------------------------
__global__ __launch_bounds__(512) void v_attn_kernel(
    const float* __restrict__ Vin,
    const bf16* __restrict__ WvT, const float* __restrict__ bvp,
    const float* __restrict__ w, bf16* __restrict__ A)
{
    __shared__ __align__(16) char smem[66560];
    char* const Xv = smem;             // [64][256] bf16 swizzled (32 KB)
    char* const VT = smem + 32768;     // [128 p][pitch 136B] (17408 B)
    char* const xS = smem + 50176;     // [64 t][16 units x 16B swizzled] (16 KB)

    const int tid  = threadIdx.x;
    const int wid  = tid >> 6, lane = tid & 63;
    const int quad = lane >> 4, l15 = lane & 15;
    const int tok0 = blockIdx.x * 64;
    const int t6   = tid & 63, dg = tid >> 6;

    #pragma unroll
    for (int it = 0; it < 4; ++it) {
        int pp = tid + (it << 9);
        int row = pp >> 5, g = pp & 31;
        const float* s = Vin + (size_t)(tok0 + row) * 256 + g * 8;
        *(uint4*)(Xv + row * 512 + ((g ^ (row & 7)) << 4)) =
            pack8(*(const float4*)s, *(const float4*)(s + 4));
    }
    float wv[64];
    {
        const float* wp = w + (size_t)(tok0 + t6) * 64;
        #pragma unroll
        for (int i = 0; i < 16; ++i) {
            float4 f = ((const float4*)wp)[i];
            wv[i*4] = f.x; wv[i*4+1] = f.y; wv[i*4+2] = f.z; wv[i*4+3] = f.w;
        }
    }
    __syncthreads();

    const int pll = wid * 16 + l15;

    for (int C = 0; C < 16; ++C) {
        f32x4 acc[4];
        #pragma unroll
        for (int mt = 0; mt < 4; ++mt)
            #pragma unroll
            for (int i = 0; i < 4; ++i) acc[mt][i] = 0.f;
        #pragma unroll
        for (int Ks = 0; Ks < 8; ++Ks) {
            bf16x8 b = *(const bf16x8*)(WvT + (size_t)(C * 128 + pll) * 256 + Ks * 32 + quad * 8);
            #pragma unroll
            for (int mt = 0; mt < 4; ++mt) {
                int row = mt * 16 + l15;
                int G = (Ks * 4 + quad) ^ (row & 7);
                bf16x8 a = *(const bf16x8*)(Xv + row * 512 + (G << 4));
                acc[mt] = MFMA16(a, b, acc[mt]);
            }
        }
        const float biv = bvp[C * 128 + pll];
        #pragma unroll
        for (int mt = 0; mt < 4; ++mt) {
            int t0 = mt * 16 + quad * 4;
            union{unsigned short us[4]; uint2 v;} pk;
            #pragma unroll
            for (int i = 0; i < 4; ++i) pk.us[i] = f2us(acc[mt][i] + biv);
            *(uint2*)(VT + pll * 136 + t0 * 2) = pk.v;
        }
        __syncthreads();
        // weighted sum: thread (t6, dg) covers d = dg*2 + {0,1}
        #pragma unroll
        for (int dd = 0; dd < 2; ++dd) {
            int d = dg * 2 + dd;
            float vv[8];
            #pragma unroll
            for (int g = 0; g < 8; ++g)
                vv[g] = us2f(*(const unsigned short*)(VT + (d * 8 + g) * 136 + t6 * 2));
            #pragma unroll
            for (int h = 0; h < 8; ++h) {
                float x = 0.f;
                #pragma unroll
                for (int g = 0; g < 8; ++g) x = fmaf(wv[h * 8 + g], vv[g], x);
                int u = (h * 2 + (d >> 3)) ^ (t6 & 15);
                *(unsigned short*)(xS + t6 * 256 + u * 16 + (d & 7) * 2) = f2us(x);
            }
        }
        __syncthreads();
        // scrambled store: thread (t, h) writes 32 B
        {
            int t = tid >> 3, hh = tid & 7;
            int tok = tok0 + t;
            int b = tok >> 11, sr = tok & 2047, sg = sr >> 3, j = sr & 7;
            size_t r = ((size_t)b << 11) + hh * 256 + sg;
            bf16* dst = A + r * 2048 + j * 256 + C * 16;
            int u0 = (hh * 2) ^ (t & 15), u1 = (hh * 2 + 1) ^ (t & 15);
            *(uint4*)dst       = *(const uint4*)(xS + t * 256 + u0 * 16);
            *(uint4*)(dst + 8) = *(const uint4*)(xS + t * 256 + u1 * 16);
        }
    }
}

// ---------------------------------------------------------------------------
// outproj: unchanged from R4.
// ---------------------------------------------------------------------------
__global__ __launch_bounds__(256) void outproj_kernel(
    const bf16* __restrict__ A, const bf16* __restrict__ WoT,
    const float* __restrict__ Wo, const float* __restrict__ bo,
    float* __restrict__ Out)
{
    __shared__ __align__(16) char smem[24576];
    char* const AsS = smem;
    char* const Ws  = smem + 8192;

    const int tid = threadIdx.x;
    const int wave = tid >> 6, lane = tid & 63, quad = lane >> 4, l15 = lane & 15;
    const int R = blockIdx.x >> 1, C = blockIdx.x & 1;
    const int row0 = R * 64, col0 = C * 128;

    f32x4 acc[4][2];
    #pragma unroll
    for (int mt = 0; mt < 4; ++mt)
        #pragma unroll
        for (int nt = 0; nt < 2; ++nt)
            #pragma unroll
            for (int i = 0; i < 4; ++i) acc[mt][nt][i] = 0.f;

    for (int kc = 0; kc < 32; ++kc) {
        __syncthreads();
        #pragma unroll
        for (int it = 0; it < 2; ++it) {
            int pp = tid + (it << 8);
            int rho = pp >> 3, g = pp & 7;
            *(uint4*)(AsS + rho * 128 + ((g ^ (rho & 7)) << 4)) =
                *(const uint4*)(A + (size_t)(row0 + rho) * 2048 + kc * 64 + g * 8);
        }
        if (WoT != nullptr) {
            #pragma unroll
            for (int it = 0; it < 4; ++it) {
                int pp = tid + (it << 8);
                int cl = pp >> 3, g = pp & 7;
                *(uint4*)(Ws + cl * 128 + ((g ^ (cl & 7)) << 4)) =
                    *(const uint4*)(WoT + (size_t)(col0 + cl) * 2048 + kc * 64 + g * 8);
            }
        } else {
            #pragma unroll
            for (int it = 0; it < 8; ++it) {
                int pp = tid + (it << 8);
                int kl = pp >> 5, c4 = (pp & 31) * 4;
                float4 f = *(const float4*)(Wo + (size_t)(kc * 64 + kl) * 256 + col0 + c4);
                float fv[4] = {f.x, f.y, f.z, f.w};
                #pragma unroll
                for (int u = 0; u < 4; ++u) {
                    int cl = c4 + u;
                    *(unsigned short*)(Ws + cl * 128 + (((kl >> 3) ^ (cl & 7)) << 4) + (kl & 7) * 2)
                        = f2us(fv[u]);
                }
            }
        }
        __syncthreads();
        #pragma unroll
        for (int ks = 0; ks < 2; ++ks) {
            bf16x8 a[4], b[2];
            #pragma unroll
            for (int mt = 0; mt < 4; ++mt) {
                int row = mt * 16 + l15;
                int G = (ks * 4 + quad) ^ (row & 7);
                a[mt] = *(const bf16x8*)(AsS + row * 128 + (G << 4));
            }
            #pragma unroll
            for (int nt = 0; nt < 2; ++nt) {
                int cl = wave * 32 + nt * 16 + l15;
                int G = (ks * 4 + quad) ^ (cl & 7);
                b[nt] = *(const bf16x8*)(Ws + cl * 128 + (G << 4));
            }
            #pragma unroll
            for (int mt = 0; mt < 4; ++mt)
                #pragma unroll
                for (int nt = 0; nt < 2; ++nt)
                    acc[mt][nt] = MFMA16(a[mt], b[nt], acc[mt][nt]);
        }
    }
    #pragma unroll
    for (int nt = 0; nt < 2; ++nt) {
        int col = col0 + wave * 32 + nt * 16 + l15;
        float bias = bo[col];
        #pragma unroll
        for (int mt = 0; mt < 4; ++mt) {
            int r0 = row0 + mt * 16 + quad * 4;
            #pragma unroll
            for (int i = 0; i < 4; ++i)
                Out[(size_t)(r0 + i) * 256 + col] = acc[mt][nt][i] + bias;
        }
    }
}

// ---------------------------------------------------------------------------
extern "C" void kernel_launch(void* const* d_in, const int* in_sizes, int n_in,
                              void* d_out, int out_size, void* d_ws, size_t ws_size,
                              hipStream_t stream) {
    const float* query = (const float*)d_in[0];
    const float* key   = (const float*)d_in[1];
    const float* value = (const float*)d_in[2];
    const int*   mask  = (const int*)  d_in[3];
    const float* Wq = (const float*)d_in[4];  const float* bq = (const float*)d_in[5];
    const float* Wk = (const float*)d_in[6];  const float* bk = (const float*)d_in[7];
    const float* Wv = (const float*)d_in[8];  const float* bv = (const float*)d_in[9];
    const float* Wo = (const float*)d_in[10]; const float* bo = (const float*)d_in[11];

    // d_out doubles as scratch; consumed before outproj overwrites d_out.
    char* dc = (char*)d_out;
    bf16*  WqT = (bf16*)dc;                    // [2048][256] bf16, 1 MB
    bf16*  WkT = (bf16*)(dc + 1048576);
    bf16*  WvT = (bf16*)(dc + 2097152);
    float* bqp = (float*)(dc + 3145728);
    float* bkp = (float*)(dc + 3153920);
    float* bvp = (float*)(dc + 3162112);
    float* w   = (float*)(dc + 3170304);       // [16384][64] fp32, 4 MB

    bf16* A = (bf16*)d_ws;                     // scrambled x_att, 64 MB
    const bool big = ws_size >= (67108864ull + 1048576ull);
    bf16* WoT = big ? (bf16*)((char*)d_ws + 67108864) : nullptr;

    prep_kernel<<<big ? 515 : 387, 256, 0, stream>>>(
        Wq, Wk, Wv, bq, bk, bv, Wo, WqT, WkT, WvT, bqp, bkp, bvp, WoT);
    qk_kernel<<<256, 512, 0, stream>>>(
        query, key, mask, WqT, WkT, bqp, bkp, w);
    v_attn_kernel<<<256, 512, 0, stream>>>(value, WvT, bvp, w, A);
    outproj_kernel<<<512, 256, 0, stream>>>(A, WoT, Wo, bo, (float*)d_out);
}